// Round 6
// baseline (1368.037 us; speedup 1.0000x reference)
//
#include <hip/hip_runtime.h>
#include <cstdint>

#define DV 2048
#define HH 16
#define DHD 128
#define LL 512
#define BB 2

typedef __attribute__((ext_vector_type(8))) short bf16x8;
typedef __attribute__((ext_vector_type(4))) float f32x4;
typedef __attribute__((ext_vector_type(4))) int i32x4;

typedef __attribute__((address_space(1))) const void* gas_cp;
typedef __attribute__((address_space(3))) void* las_p;

__device__ __forceinline__ void gll16(const void* g, void* l) {
    __builtin_amdgcn_global_load_lds((gas_cp)g, (las_p)l, 16, 0, 0);
}

__device__ __forceinline__ unsigned short f2b(float f) {
    union { float f; unsigned int u; } v; v.f = f;
    unsigned int u = v.u;
    return (unsigned short)((u + 0x7FFFu + ((u >> 16) & 1u)) >> 16);
}

// ---------------- elementwise f32 -> bf16 ----------------
__global__ void cvt_k(const float* __restrict__ in, ushort* __restrict__ out, long n) {
    long stride = (long)gridDim.x * blockDim.x * 4;
    for (long i = ((long)blockIdx.x * blockDim.x + threadIdx.x) * 4; i < n; i += stride) {
        float4 f = *(const float4*)(in + i);
        *(ushort4*)(out + i) = make_ushort4(f2b(f.x), f2b(f.y), f2b(f.z), f2b(f.w));
    }
}

// ---------------- transpose + convert: out[c][r] = in[r][c] ----------------
__global__ void transpose_cvt_k(const float* __restrict__ in, ushort* __restrict__ outp,
                                int R, int C) {
    __shared__ float tile[64][65];
    int c0 = blockIdx.x * 64, r0 = blockIdx.y * 64;
    int tx = threadIdx.x & 63, ty = threadIdx.x >> 6;
#pragma unroll
    for (int p = 0; p < 16; ++p)
        tile[ty + p * 4][tx] = in[(long)(r0 + ty + p * 4) * C + c0 + tx];
    __syncthreads();
#pragma unroll
    for (int p = 0; p < 16; ++p)
        outp[(long)(c0 + ty + p * 4) * R + r0 + tx] = f2b(tile[tx][ty + p * 4]);
}

// ---------------- kv_cache -> c_kv out (f32) + bf16 copy ----------------
__global__ void kvcopy_k(const float* __restrict__ kv, float* __restrict__ cko,
                         ushort* __restrict__ ckb, int PAST, int T) {
    long n = (long)BB * PAST * LL;
    long pl2 = (long)PAST * LL;
    long stride = (long)gridDim.x * blockDim.x * 4;
    for (long i = ((long)blockIdx.x * blockDim.x + threadIdx.x) * 4; i < n; i += stride) {
        float4 f = *(const float4*)(kv + i);
        long b = i / pl2, wloc = i - b * pl2;
        long o = b * (long)T * LL + wloc;
        *(float4*)(cko + o) = f;
        *(ushort4*)(ckb + o) = make_ushort4(f2b(f.x), f2b(f.y), f2b(f.z), f2b(f.w));
    }
}

// ---------------- LayerNorm over L=512, one wave per row ----------------
__global__ __launch_bounds__(256) void ln_k(const float* __restrict__ cpre,
                                            const float* __restrict__ g, const float* __restrict__ be,
                                            float* __restrict__ cko, ushort* __restrict__ ckb,
                                            int S, int PAST, int T) {
    int wid = threadIdx.x >> 6, lane = threadIdx.x & 63;
    int row = blockIdx.x * 4 + wid;
    int b = row / S, s = row - b * S;
    const float* xr = cpre + (long)row * LL + lane * 8;
    float4 v0 = *(const float4*)xr;
    float4 v1 = *(const float4*)(xr + 4);
    float sum = v0.x + v0.y + v0.z + v0.w + v1.x + v1.y + v1.z + v1.w;
    float sq = v0.x * v0.x + v0.y * v0.y + v0.z * v0.z + v0.w * v0.w +
               v1.x * v1.x + v1.y * v1.y + v1.z * v1.z + v1.w * v1.w;
#pragma unroll
    for (int m = 1; m < 64; m <<= 1) { sum += __shfl_xor(sum, m, 64); sq += __shfl_xor(sq, m, 64); }
    float mu = sum * (1.0f / LL);
    float var = sq * (1.0f / LL) - mu * mu;
    float rstd = rsqrtf(var + 1e-5f);
    const float* gp = g + lane * 8;
    const float* bp = be + lane * 8;
    float4 g0 = *(const float4*)gp, g1 = *(const float4*)(gp + 4);
    float4 b0 = *(const float4*)bp, b1 = *(const float4*)(bp + 4);
    float y0 = (v0.x - mu) * rstd * g0.x + b0.x;
    float y1 = (v0.y - mu) * rstd * g0.y + b0.y;
    float y2 = (v0.z - mu) * rstd * g0.z + b0.z;
    float y3 = (v0.w - mu) * rstd * g0.w + b0.w;
    float y4 = (v1.x - mu) * rstd * g1.x + b1.x;
    float y5 = (v1.y - mu) * rstd * g1.y + b1.y;
    float y6 = (v1.z - mu) * rstd * g1.z + b1.z;
    float y7 = (v1.w - mu) * rstd * g1.w + b1.w;
    long o = ((long)b * T + PAST + s) * LL + lane * 8;
    *(float4*)(cko + o) = make_float4(y0, y1, y2, y3);
    *(float4*)(cko + o + 4) = make_float4(y4, y5, y6, y7);
    *(ushort4*)(ckb + o) = make_ushort4(f2b(y0), f2b(y1), f2b(y2), f2b(y3));
    *(ushort4*)(ckb + o + 4) = make_ushort4(f2b(y4), f2b(y5), f2b(y6), f2b(y7));
}

// ---------------- generic NT GEMM: C[M,N] = cscale * A[M,K] * B[N,K]^T ----------------
template <bool OUT_BF16>
__global__ __launch_bounds__(256, 2) void gemm_nt(const ushort* __restrict__ A,
                                                  const ushort* __restrict__ B,
                                                  void* __restrict__ Cv,
                                                  int K, int lda, int ldb, int ldc,
                                                  long aHi, long aLo, long bHi, long bLo,
                                                  long cHi, long cLo, int zdiv, float cscale) {
    __shared__ __align__(16) ushort Asm[128 * 72];
    __shared__ __align__(16) ushort Bsm[128 * 72];
    const int tid = threadIdx.x, wid = tid >> 6, lane = tid & 63;
    const int z = blockIdx.z, zh = z / zdiv, zl = z % zdiv;
    A += zh * aHi + zl * aLo;
    B += zh * bHi + zl * bLo;
    const long cOff = zh * cHi + zl * cLo;
    const int m0 = blockIdx.x * 128, n0 = blockIdx.y * 128;
    const int wm = (wid >> 1) * 64, wn = (wid & 1) * 64;
    f32x4 acc[4][4] = {};
    const int l8 = lane & 7;
    const int rowA = wid * 8 + (lane >> 3);
    const ushort* Ag = A + (long)(m0 + rowA) * lda + l8 * 8;
    const ushort* Bg = B + (long)(n0 + rowA) * ldb + l8 * 8;

    i32x4 ra[4], rb[4];
#pragma unroll
    for (int p = 0; p < 4; ++p) {
        ra[p] = *(const i32x4*)(Ag + (long)p * 32 * lda);
        rb[p] = *(const i32x4*)(Bg + (long)p * 32 * ldb);
    }
    for (int kt = 0; kt < K; kt += 64) {
        __syncthreads();
#pragma unroll
        for (int p = 0; p < 4; ++p) {
            *(i32x4*)(Asm + (p * 32 + rowA) * 72 + l8 * 8) = ra[p];
            *(i32x4*)(Bsm + (p * 32 + rowA) * 72 + l8 * 8) = rb[p];
        }
        __syncthreads();
        if (kt + 64 < K) {
#pragma unroll
            for (int p = 0; p < 4; ++p) {
                ra[p] = *(const i32x4*)(Ag + (long)p * 32 * lda + kt + 64);
                rb[p] = *(const i32x4*)(Bg + (long)p * 32 * ldb + kt + 64);
            }
        }
#pragma unroll
        for (int kk = 0; kk < 2; ++kk) {
            const int ko = kk * 32 + ((lane >> 4) << 3);
            bf16x8 af[4], bf[4];
#pragma unroll
            for (int i = 0; i < 4; ++i)
                af[i] = *(const bf16x8*)(Asm + (wm + i * 16 + (lane & 15)) * 72 + ko);
#pragma unroll
            for (int j = 0; j < 4; ++j)
                bf[j] = *(const bf16x8*)(Bsm + (wn + j * 16 + (lane & 15)) * 72 + ko);
#pragma unroll
            for (int i = 0; i < 4; ++i)
#pragma unroll
                for (int j = 0; j < 4; ++j)
                    acc[i][j] = __builtin_amdgcn_mfma_f32_16x16x32_bf16(af[i], bf[j], acc[i][j], 0, 0, 0);
        }
        __syncthreads();
    }
    const int cr = (lane >> 4) * 4, cc = lane & 15;
#pragma unroll
    for (int i = 0; i < 4; ++i) {
#pragma unroll
        for (int r = 0; r < 4; ++r) {
            const long row = m0 + wm + i * 16 + cr + r;
#pragma unroll
            for (int j = 0; j < 4; ++j) {
                const long col = n0 + wn + j * 16 + cc;
                if (OUT_BF16)
                    ((ushort*)Cv)[cOff + row * ldc + col] = f2b(acc[i][j][r] * cscale);
                else
                    ((float*)Cv)[cOff + row * ldc + col] = acc[i][j][r] * cscale;
            }
        }
    }
}

// ---------------- flash attention (round 6) ----------------
// 4 waves = 2(q) x 2(t): each wave 32 q-rows x 32 t-cols for QK (2 A-frags per
// B-read -> K LDS reads halved) and 32 q x 64 d-half for PV. Staging stream
// [K0,K1,K2,K3,V] through 3 rotating buffers, counted vmcnt(4) (round-5
// rotation, verified). Softmax: t-split partners exchange row-max / partial
// sums via small LDS buffer (+2 s_barriers per tile).
#define PH_WAIT4()                                               \
    do {                                                         \
        asm volatile("s_waitcnt vmcnt(4) lgkmcnt(0)" ::: "memory"); \
        __builtin_amdgcn_s_barrier();                            \
    } while (0)
#define PH_WAIT0()                                               \
    do {                                                         \
        asm volatile("s_waitcnt vmcnt(0) lgkmcnt(0)" ::: "memory"); \
        __builtin_amdgcn_s_barrier();                            \
    } while (0)
#define LG_BAR()                                                 \
    do {                                                         \
        asm volatile("s_waitcnt lgkmcnt(0)" ::: "memory");       \
        __builtin_amdgcn_s_barrier();                            \
    } while (0)

__global__ __launch_bounds__(256) void attn_k(const ushort* __restrict__ tmpb,
                                              const ushort* __restrict__ ckvb,
                                              const ushort* __restrict__ vtb,
                                              ushort* __restrict__ ctxb,
                                              int S, int T, int PAST) {
    __shared__ __align__(16) ushort buf[3][8192];  // K view: [64][128]; V view: [128][64]
    __shared__ __align__(16) ushort pl[64][72];    // P [q64][t64+8pad]
    __shared__ float sm_m[2][2][32];               // [wt][wq][row] partial max
    __shared__ float sm_s[2][2][32];               // [wt][wq][row] partial sum
    const int tid = threadIdx.x, wid = tid >> 6, lane = tid & 63;
    const int wq = wid >> 1, wt = wid & 1;
    const int h = blockIdx.y, b = blockIdx.z;
    const int s0 = ((int)gridDim.x - 1 - (int)blockIdx.x) * 64;  // longest-first

    const int g = lane >> 4;       // 0..3
    const int l15 = lane & 15;
    const int q8 = g << 3;
    const int swr = (l15 & 7) << 3;  // read-side XOR (ushort units)

    // Q: 32 rows (wq*32 + aq*16 + l15) x 512 L, fully resident (128 VGPR)
    bf16x8 qf[32];  // [aq*16 + c*4 + kk]
    {
        const ushort* qb = tmpb + ((long)(b * HH + h) * S + s0 + wq * 32 + l15) * LL + q8;
#pragma unroll
        for (int aq = 0; aq < 2; ++aq)
#pragma unroll
            for (int c = 0; c < 4; ++c)
#pragma unroll
                for (int kk = 0; kk < 4; ++kk)
                    qf[aq * 16 + c * 4 + kk] =
                        *(const bf16x8*)(qb + (long)aq * 16 * LL + c * 128 + kk * 32);
    }
    f32x4 cacc[2][4] = {};   // [aq][df] : 32q x 64d(wt half)
    f32x4 sacc[2][2] = {};   // [aq][nf] : 32q x 32t(wt half)
    float mrow[8], lrow[8];  // [aq*4+r]
#pragma unroll
    for (int i = 0; i < 8; ++i) { mrow[i] = -1e30f; lrow[i] = 0.f; }

    const int rl = tid >> 4, cc16 = tid & 15;  // K staging coords
    const int vr = tid >> 3, vc = tid & 7;     // V staging coords
    const int nfull = (s0 + PAST) / 64;
    const ushort* kbase = ckvb + (long)b * T * LL;
    const ushort* vbase = vtb + ((long)b * DV + h * DHD) * T;
    const int kcol = (cc16 ^ (rl & 7)) << 3;   // pre-swizzled K source column
    const int vcol = (vc ^ (vr & 7)) << 3;     // pre-swizzled V source column

    auto stageK = [&](int tt_, int c_, int bi) {
#pragma unroll
        for (int p = 0; p < 4; ++p)
            gll16(kbase + (long)(tt_ * 64 + p * 16 + rl) * LL + c_ * 128 + kcol,
                  &buf[bi][p * 2048 + tid * 8]);
    };
    auto stageV = [&](int tt_, int bi) {
#pragma unroll
        for (int p = 0; p < 4; ++p)
            gll16(vbase + (long)(p * 32 + vr) * T + tt_ * 64 + vcol,
                  &buf[bi][p * 2048 + tid * 8]);
    };

#define QK_CHUNK(C, BP)                                                                   \
    do {                                                                                  \
        const ushort* kb_ = &buf[BP][(wt * 32) * 128];                                    \
        __builtin_amdgcn_s_setprio(1);                                                    \
        _Pragma("unroll") for (int kk = 0; kk < 4; ++kk) {                                \
            const int ko = kk * 32 + q8;                                                  \
            _Pragma("unroll") for (int nf = 0; nf < 2; ++nf) {                            \
                bf16x8 bfr = *(const bf16x8*)(&kb_[(nf * 16 + l15) * 128 + (ko ^ swr)]);  \
                sacc[0][nf] = __builtin_amdgcn_mfma_f32_16x16x32_bf16(                    \
                    qf[(C) * 4 + kk], bfr, sacc[0][nf], 0, 0, 0);                         \
                sacc[1][nf] = __builtin_amdgcn_mfma_f32_16x16x32_bf16(                    \
                    qf[16 + (C) * 4 + kk], bfr, sacc[1][nf], 0, 0, 0);                    \
            }                                                                             \
        }                                                                                 \
        __builtin_amdgcn_s_setprio(0);                                                    \
    } while (0)

    // prologue: stream items 0,1 = K(0,0)->buf0, K(0,1)->buf1
    stageK(0, 0, 0);
    stageK(0, 1, 1);
    int bi0 = 0;

    for (int tt = 0; tt <= nfull; ++tt) {
        const bool last = (tt == nfull);
        int bA = bi0;
        int bB = bi0 + 1; if (bB >= 3) bB -= 3;
        int bC = bi0 + 2; if (bC >= 3) bC -= 3;
        PH_WAIT4();
        stageK(tt, 2, bC);
        QK_CHUNK(0, bA);
        PH_WAIT4();
        stageK(tt, 3, bA);
        QK_CHUNK(1, bB);
        PH_WAIT4();
        stageV(tt, bB);
        QK_CHUNK(2, bC);
        PH_WAIT4();
        if (!last) stageK(tt + 1, 0, bC);
        QK_CHUNK(3, bA);
        if (last) { PH_WAIT0(); } else { PH_WAIT4(); }
        if (!last) stageK(tt + 1, 1, bA);
        // ---- softmax: partial max over own t-half ----
        float pm[8];
#pragma unroll
        for (int aq = 0; aq < 2; ++aq)
#pragma unroll
            for (int r = 0; r < 4; ++r) {
                float m0 = -1e30f;
#pragma unroll
                for (int nf = 0; nf < 2; ++nf) {
                    float v = sacc[aq][nf][r];
                    if (last) {
                        int tcol = wt * 32 + nf * 16 + l15;
                        int qrl = wq * 32 + aq * 16 + g * 4 + r;
                        if (tcol > qrl) v = -1e30f;
                    }
                    sacc[aq][nf][r] = v;
                    m0 = fmaxf(m0, v);
                }
                pm[aq * 4 + r] = m0;
            }
#pragma unroll
        for (int i = 0; i < 8; ++i)
#pragma unroll
            for (int m = 1; m < 16; m <<= 1) pm[i] = fmaxf(pm[i], __shfl_xor(pm[i], m, 64));
        if (l15 == 0) {
#pragma unroll
            for (int aq = 0; aq < 2; ++aq)
#pragma unroll
                for (int r = 0; r < 4; ++r)
                    sm_m[wt][wq][aq * 16 + g * 4 + r] = pm[aq * 4 + r];
        }
        LG_BAR();
        // combined max
#pragma unroll
        for (int aq = 0; aq < 2; ++aq)
#pragma unroll
            for (int r = 0; r < 4; ++r)
                pm[aq * 4 + r] = fmaxf(pm[aq * 4 + r], sm_m[wt ^ 1][wq][aq * 16 + g * 4 + r]);
        // defer-max: both wt-partners see identical pm/mrow -> identical decision
        bool need = false;
#pragma unroll
        for (int i = 0; i < 8; ++i) need |= (pm[i] > mrow[i] + 8.0f);
        if (__any(need)) {
#pragma unroll
            for (int aq = 0; aq < 2; ++aq)
#pragma unroll
                for (int r = 0; r < 4; ++r) {
                    const int i = aq * 4 + r;
                    float mn = fmaxf(mrow[i], pm[i]);
                    float al = __expf(mrow[i] - mn);
                    mrow[i] = mn;
                    lrow[i] *= al;
#pragma unroll
                    for (int df = 0; df < 4; ++df) cacc[aq][df][r] *= al;
                }
        }
        // exp + partial sums + P write
        float ps[8] = {0.f, 0.f, 0.f, 0.f, 0.f, 0.f, 0.f, 0.f};
#pragma unroll
        for (int aq = 0; aq < 2; ++aq)
#pragma unroll
            for (int nf = 0; nf < 2; ++nf)
#pragma unroll
                for (int r = 0; r < 4; ++r) {
                    float p = __expf(sacc[aq][nf][r] - mrow[aq * 4 + r]);
                    sacc[aq][nf][r] = p;
                    ps[aq * 4 + r] += p;
                }
#pragma unroll
        for (int i = 0; i < 8; ++i)
#pragma unroll
            for (int m = 1; m < 16; m <<= 1) ps[i] += __shfl_xor(ps[i], m, 64);
#pragma unroll
        for (int aq = 0; aq < 2; ++aq)
#pragma unroll
            for (int nf = 0; nf < 2; ++nf)
#pragma unroll
                for (int r = 0; r < 4; ++r)
                    pl[wq * 32 + aq * 16 + g * 4 + r][wt * 32 + nf * 16 + l15] =
                        f2b(sacc[aq][nf][r]);
        if (l15 == 0) {
#pragma unroll
            for (int aq = 0; aq < 2; ++aq)
#pragma unroll
                for (int r = 0; r < 4; ++r)
                    sm_s[wt][wq][aq * 16 + g * 4 + r] = ps[aq * 4 + r];
        }
        LG_BAR();
#pragma unroll
        for (int aq = 0; aq < 2; ++aq)
#pragma unroll
            for (int r = 0; r < 4; ++r)
                lrow[aq * 4 + r] += ps[aq * 4 + r] + sm_s[wt ^ 1][wq][aq * 16 + g * 4 + r];
#pragma unroll
        for (int aq = 0; aq < 2; ++aq)
#pragma unroll
            for (int nf = 0; nf < 2; ++nf) sacc[aq][nf] = (f32x4){0.f, 0.f, 0.f, 0.f};
        // ---- ctx += P * V : wave's d-half, full t=64 ----
        {
            const ushort* vb_ = &buf[bB][0];
            __builtin_amdgcn_s_setprio(1);
#pragma unroll
            for (int kk = 0; kk < 2; ++kk) {
                bf16x8 pa0 = *(const bf16x8*)(&pl[wq * 32 + l15][kk * 32 + q8]);
                bf16x8 pa1 = *(const bf16x8*)(&pl[wq * 32 + 16 + l15][kk * 32 + q8]);
#pragma unroll
                for (int df = 0; df < 4; ++df) {
                    bf16x8 bv = *(const bf16x8*)(&vb_[(wt * 64 + df * 16 + l15) * 64 +
                                                      ((kk * 32 + q8) ^ swr)]);
                    cacc[0][df] = __builtin_amdgcn_mfma_f32_16x16x32_bf16(pa0, bv, cacc[0][df], 0, 0, 0);
                    cacc[1][df] = __builtin_amdgcn_mfma_f32_16x16x32_bf16(pa1, bv, cacc[1][df], 0, 0, 0);
                }
            }
            __builtin_amdgcn_s_setprio(0);
        }
        bi0 = bC;
    }
    // ---- epilogue: wave's 32 q-rows x 64 d-half ----
#pragma unroll
    for (int aq = 0; aq < 2; ++aq)
#pragma unroll
        for (int r = 0; r < 4; ++r) {
            float inv = 1.0f / lrow[aq * 4 + r];
            const long row = (long)b * S + s0 + wq * 32 + aq * 16 + g * 4 + r;
            const int d = h * DHD + wt * 64 + l15;
#pragma unroll
            for (int df = 0; df < 4; ++df)
                ctxb[row * DV + d + df * 16] = f2b(cacc[aq][df][r] * inv);
        }
}

extern "C" void kernel_launch(void* const* d_in, const int* in_sizes, int n_in,
                              void* d_out, int out_size, void* d_ws, size_t ws_size,
                              hipStream_t stream) {
    const float* x = (const float*)d_in[0];
    const float* kv = (const float*)d_in[1];
    const float* Wq = (const float*)d_in[2];
    const float* Wdkv = (const float*)d_in[3];
    const float* Wuk = (const float*)d_in[4];
    const float* Wuv = (const float*)d_in[5];
    const float* Wo = (const float*)d_in[6];
    const float* lng = (const float*)d_in[7];
    const float* lnbt = (const float*)d_in[8];
    const int S = in_sizes[0] / (BB * DV);     // 2048
    const int PAST = in_sizes[1] / (BB * LL);  // 2048
    const int T = S + PAST;                    // 4096

    float* out_p = (float*)d_out;                       // [B,S,D] f32
    float* ckv_out = out_p + (size_t)BB * S * DV;       // [B,T,L] f32

    char* w = (char*)d_ws;
    auto take = [&](size_t bytes) { char* p = w; w += (bytes + 255) & ~(size_t)255; return p; };
    ushort* xb    = (ushort*)take((size_t)BB * S * DV * 2);
    ushort* Wqb   = (ushort*)take((size_t)DV * DV * 2);
    ushort* WukT  = (ushort*)take((size_t)DV * LL * 2);   // [L][D]
    ushort* Wdkvb = (ushort*)take((size_t)LL * DV * 2);
    ushort* Wuvb  = (ushort*)take((size_t)DV * LL * 2);
    ushort* Wob   = (ushort*)take((size_t)DV * DV * 2);
    ushort* absT  = (ushort*)take((size_t)LL * DV * 2);   // [L][D] = absorbed^T
    float*  cpre  = (float*)take((size_t)BB * S * LL * 4);
    ushort* ckvb  = (ushort*)take((size_t)BB * T * LL * 2);
    ushort* vtb   = (ushort*)take((size_t)BB * DV * T * 2); // [B][D][T]
    ushort* tmpb  = (ushort*)take((size_t)BB * HH * S * LL * 2);
    ushort* ctxb  = (ushort*)take((size_t)BB * S * DV * 2);

    auto cvt = [&](const float* in, ushort* op, long n) {
        long nb = (n / 4 + 255) / 256;
        if (nb > 2048) nb = 2048;
        cvt_k<<<dim3((unsigned)nb), dim3(256), 0, stream>>>(in, op, n);
    };
    cvt(x, xb, (long)BB * S * DV);
    cvt(Wq, Wqb, (long)DV * DV);
    cvt(Wdkv, Wdkvb, (long)LL * DV);
    cvt(Wuv, Wuvb, (long)DV * LL);
    cvt(Wo, Wob, (long)DV * DV);
    transpose_cvt_k<<<dim3(LL / 64, DV / 64), dim3(256), 0, stream>>>(Wuk, WukT, DV, LL);
    kvcopy_k<<<dim3(2048), dim3(256), 0, stream>>>(kv, ckv_out, ckvb, PAST, T);

    // absorbed^T[l,i] = sum_k WukT[l,k] * Wq[i,k]
    gemm_nt<true><<<dim3(LL / 128, DV / 128, 1), dim3(256), 0, stream>>>(
        WukT, Wqb, absT, DV, DV, DV, DV, 0, 0, 0, 0, 0, 0, 1, 1.0f);
    // c_pre = x * Wdkv^T  (f32)
    gemm_nt<false><<<dim3(BB * S / 128, LL / 128, 1), dim3(256), 0, stream>>>(
        xb, Wdkvb, cpre, DV, DV, DV, LL, 0, 0, 0, 0, 0, 0, 1, 1.0f);
    ln_k<<<dim3(BB * S / 4), dim3(256), 0, stream>>>(cpre, lng, lnbt, ckv_out, ckvb, S, PAST, T);
    // Vt[b] = Wuv * ckv[b]^T : [D][T] bf16
    gemm_nt<true><<<dim3(DV / 128, T / 128, BB), dim3(256), 0, stream>>>(
        Wuvb, ckvb, vtb, LL, LL, LL, T, 0, 0, (long)T * LL, 0, (long)DV * T, 0, 1, 1.0f);
    // tmp[b,h] = x_h * absorbed_h^T, pre-scaled by 1/sqrt(dh)
    gemm_nt<true><<<dim3(S / 128, LL / 128, BB * HH), dim3(256), 0, stream>>>(
        xb, absT, tmpb, DHD, DV, DV, LL,
        (long)S * DV, DHD, 0, DHD, (long)HH * S * LL, (long)S * LL, HH,
        0.08838834764831845f);
    // attention
    attn_k<<<dim3(S / 64, HH, BB), dim3(256), 0, stream>>>(tmpb, ckvb, vtb, ctxb, S, T, PAST);
    // out = ctx * Wo^T (f32)
    gemm_nt<false><<<dim3(BB * S / 128, DV / 128, 1), dim3(256), 0, stream>>>(
        ctxb, Wob, out_p, DV, DV, DV, DV, 0, 0, 0, 0, 0, 0, 1, 1.0f);
}

// Round 7
// 890.750 us; speedup vs baseline: 1.5358x; 1.5358x over previous
//
#include <hip/hip_runtime.h>
#include <cstdint>

#define DV 2048
#define HH 16
#define DHD 128
#define LL 512
#define BB 2

typedef __attribute__((ext_vector_type(8))) short bf16x8;
typedef __attribute__((ext_vector_type(4))) float f32x4;
typedef __attribute__((ext_vector_type(4))) int i32x4;

typedef __attribute__((address_space(1))) const void* gas_cp;
typedef __attribute__((address_space(3))) void* las_p;

__device__ __forceinline__ void gll16(const void* g, void* l) {
    __builtin_amdgcn_global_load_lds((gas_cp)g, (las_p)l, 16, 0, 0);
}

__device__ __forceinline__ unsigned short f2b(float f) {
    union { float f; unsigned int u; } v; v.f = f;
    unsigned int u = v.u;
    return (unsigned short)((u + 0x7FFFu + ((u >> 16) & 1u)) >> 16);
}

// ---------------- elementwise f32 -> bf16 ----------------
__global__ void cvt_k(const float* __restrict__ in, ushort* __restrict__ out, long n) {
    long stride = (long)gridDim.x * blockDim.x * 4;
    for (long i = ((long)blockIdx.x * blockDim.x + threadIdx.x) * 4; i < n; i += stride) {
        float4 f = *(const float4*)(in + i);
        *(ushort4*)(out + i) = make_ushort4(f2b(f.x), f2b(f.y), f2b(f.z), f2b(f.w));
    }
}

// ---------------- transpose + convert: out[c][r] = in[r][c] ----------------
__global__ void transpose_cvt_k(const float* __restrict__ in, ushort* __restrict__ outp,
                                int R, int C) {
    __shared__ float tile[64][65];
    int c0 = blockIdx.x * 64, r0 = blockIdx.y * 64;
    int tx = threadIdx.x & 63, ty = threadIdx.x >> 6;
#pragma unroll
    for (int p = 0; p < 16; ++p)
        tile[ty + p * 4][tx] = in[(long)(r0 + ty + p * 4) * C + c0 + tx];
    __syncthreads();
#pragma unroll
    for (int p = 0; p < 16; ++p)
        outp[(long)(c0 + ty + p * 4) * R + r0 + tx] = f2b(tile[tx][ty + p * 4]);
}

// ---------------- kv_cache -> c_kv out (f32) + bf16 copy ----------------
__global__ void kvcopy_k(const float* __restrict__ kv, float* __restrict__ cko,
                         ushort* __restrict__ ckb, int PAST, int T) {
    long n = (long)BB * PAST * LL;
    long pl2 = (long)PAST * LL;
    long stride = (long)gridDim.x * blockDim.x * 4;
    for (long i = ((long)blockIdx.x * blockDim.x + threadIdx.x) * 4; i < n; i += stride) {
        float4 f = *(const float4*)(kv + i);
        long b = i / pl2, wloc = i - b * pl2;
        long o = b * (long)T * LL + wloc;
        *(float4*)(cko + o) = f;
        *(ushort4*)(ckb + o) = make_ushort4(f2b(f.x), f2b(f.y), f2b(f.z), f2b(f.w));
    }
}

// ---------------- LayerNorm over L=512, one wave per row ----------------
__global__ __launch_bounds__(256) void ln_k(const float* __restrict__ cpre,
                                            const float* __restrict__ g, const float* __restrict__ be,
                                            float* __restrict__ cko, ushort* __restrict__ ckb,
                                            int S, int PAST, int T) {
    int wid = threadIdx.x >> 6, lane = threadIdx.x & 63;
    int row = blockIdx.x * 4 + wid;
    int b = row / S, s = row - b * S;
    const float* xr = cpre + (long)row * LL + lane * 8;
    float4 v0 = *(const float4*)xr;
    float4 v1 = *(const float4*)(xr + 4);
    float sum = v0.x + v0.y + v0.z + v0.w + v1.x + v1.y + v1.z + v1.w;
    float sq = v0.x * v0.x + v0.y * v0.y + v0.z * v0.z + v0.w * v0.w +
               v1.x * v1.x + v1.y * v1.y + v1.z * v1.z + v1.w * v1.w;
#pragma unroll
    for (int m = 1; m < 64; m <<= 1) { sum += __shfl_xor(sum, m, 64); sq += __shfl_xor(sq, m, 64); }
    float mu = sum * (1.0f / LL);
    float var = sq * (1.0f / LL) - mu * mu;
    float rstd = rsqrtf(var + 1e-5f);
    const float* gp = g + lane * 8;
    const float* bp = be + lane * 8;
    float4 g0 = *(const float4*)gp, g1 = *(const float4*)(gp + 4);
    float4 b0 = *(const float4*)bp, b1 = *(const float4*)(bp + 4);
    float y0 = (v0.x - mu) * rstd * g0.x + b0.x;
    float y1 = (v0.y - mu) * rstd * g0.y + b0.y;
    float y2 = (v0.z - mu) * rstd * g0.z + b0.z;
    float y3 = (v0.w - mu) * rstd * g0.w + b0.w;
    float y4 = (v1.x - mu) * rstd * g1.x + b1.x;
    float y5 = (v1.y - mu) * rstd * g1.y + b1.y;
    float y6 = (v1.z - mu) * rstd * g1.z + b1.z;
    float y7 = (v1.w - mu) * rstd * g1.w + b1.w;
    long o = ((long)b * T + PAST + s) * LL + lane * 8;
    *(float4*)(cko + o) = make_float4(y0, y1, y2, y3);
    *(float4*)(cko + o + 4) = make_float4(y4, y5, y6, y7);
    *(ushort4*)(ckb + o) = make_ushort4(f2b(y0), f2b(y1), f2b(y2), f2b(y3));
    *(ushort4*)(ckb + o + 4) = make_ushort4(f2b(y4), f2b(y5), f2b(y6), f2b(y7));
}

// ---------------- generic NT GEMM: C[M,N] = cscale * A[M,K] * B[N,K]^T ----------------
template <bool OUT_BF16>
__global__ __launch_bounds__(256, 2) void gemm_nt(const ushort* __restrict__ A,
                                                  const ushort* __restrict__ B,
                                                  void* __restrict__ Cv,
                                                  int K, int lda, int ldb, int ldc,
                                                  long aHi, long aLo, long bHi, long bLo,
                                                  long cHi, long cLo, int zdiv, float cscale) {
    __shared__ __align__(16) ushort Asm[128 * 72];
    __shared__ __align__(16) ushort Bsm[128 * 72];
    const int tid = threadIdx.x, wid = tid >> 6, lane = tid & 63;
    const int z = blockIdx.z, zh = z / zdiv, zl = z % zdiv;
    A += zh * aHi + zl * aLo;
    B += zh * bHi + zl * bLo;
    const long cOff = zh * cHi + zl * cLo;
    const int m0 = blockIdx.x * 128, n0 = blockIdx.y * 128;
    const int wm = (wid >> 1) * 64, wn = (wid & 1) * 64;
    f32x4 acc[4][4] = {};
    const int l8 = lane & 7;
    const int rowA = wid * 8 + (lane >> 3);
    const ushort* Ag = A + (long)(m0 + rowA) * lda + l8 * 8;
    const ushort* Bg = B + (long)(n0 + rowA) * ldb + l8 * 8;

    i32x4 ra[4], rb[4];
#pragma unroll
    for (int p = 0; p < 4; ++p) {
        ra[p] = *(const i32x4*)(Ag + (long)p * 32 * lda);
        rb[p] = *(const i32x4*)(Bg + (long)p * 32 * ldb);
    }
    for (int kt = 0; kt < K; kt += 64) {
        __syncthreads();
#pragma unroll
        for (int p = 0; p < 4; ++p) {
            *(i32x4*)(Asm + (p * 32 + rowA) * 72 + l8 * 8) = ra[p];
            *(i32x4*)(Bsm + (p * 32 + rowA) * 72 + l8 * 8) = rb[p];
        }
        __syncthreads();
        if (kt + 64 < K) {
#pragma unroll
            for (int p = 0; p < 4; ++p) {
                ra[p] = *(const i32x4*)(Ag + (long)p * 32 * lda + kt + 64);
                rb[p] = *(const i32x4*)(Bg + (long)p * 32 * ldb + kt + 64);
            }
        }
#pragma unroll
        for (int kk = 0; kk < 2; ++kk) {
            const int ko = kk * 32 + ((lane >> 4) << 3);
            bf16x8 af[4], bf[4];
#pragma unroll
            for (int i = 0; i < 4; ++i)
                af[i] = *(const bf16x8*)(Asm + (wm + i * 16 + (lane & 15)) * 72 + ko);
#pragma unroll
            for (int j = 0; j < 4; ++j)
                bf[j] = *(const bf16x8*)(Bsm + (wn + j * 16 + (lane & 15)) * 72 + ko);
#pragma unroll
            for (int i = 0; i < 4; ++i)
#pragma unroll
                for (int j = 0; j < 4; ++j)
                    acc[i][j] = __builtin_amdgcn_mfma_f32_16x16x32_bf16(af[i], bf[j], acc[i][j], 0, 0, 0);
        }
        __syncthreads();
    }
    const int cr = (lane >> 4) * 4, cc = lane & 15;
#pragma unroll
    for (int i = 0; i < 4; ++i) {
#pragma unroll
        for (int r = 0; r < 4; ++r) {
            const long row = m0 + wm + i * 16 + cr + r;
#pragma unroll
            for (int j = 0; j < 4; ++j) {
                const long col = n0 + wn + j * 16 + cc;
                if (OUT_BF16)
                    ((ushort*)Cv)[cOff + row * ldc + col] = f2b(acc[i][j][r] * cscale);
                else
                    ((float*)Cv)[cOff + row * ldc + col] = acc[i][j][r] * cscale;
            }
        }
    }
}

// ---------------- flash attention (round 7) ----------------
// Round-6 structure (4 waves = 2q x 2t, R=32 q-rows/wave, halved LDS reads)
// with the Q-rematerialization bug fixed: __launch_bounds__(256,2) raises the
// VGPR budget to 256 (LDS already caps at 2 blocks/CU), and qf is pinned via
// an empty asm redefinition so the 32 Q-fragment loads cannot be sunk into
// the tile loop (which was also poisoning the counted-vmcnt pipeline).
#define PH_WAIT4()                                               \
    do {                                                         \
        asm volatile("s_waitcnt vmcnt(4) lgkmcnt(0)" ::: "memory"); \
        __builtin_amdgcn_s_barrier();                            \
    } while (0)
#define PH_WAIT0()                                               \
    do {                                                         \
        asm volatile("s_waitcnt vmcnt(0) lgkmcnt(0)" ::: "memory"); \
        __builtin_amdgcn_s_barrier();                            \
    } while (0)
#define LG_BAR()                                                 \
    do {                                                         \
        asm volatile("s_waitcnt lgkmcnt(0)" ::: "memory");       \
        __builtin_amdgcn_s_barrier();                            \
    } while (0)

__global__ __launch_bounds__(256, 2) void attn_k(const ushort* __restrict__ tmpb,
                                                 const ushort* __restrict__ ckvb,
                                                 const ushort* __restrict__ vtb,
                                                 ushort* __restrict__ ctxb,
                                                 int S, int T, int PAST) {
    __shared__ __align__(16) ushort buf[3][8192];  // K view: [64][128]; V view: [128][64]
    __shared__ __align__(16) ushort pl[64][72];    // P [q64][t64+8pad]
    __shared__ float sm_m[2][2][32];               // [wt][wq][row] partial max
    __shared__ float sm_s[2][2][32];               // [wt][wq][row] partial sum
    const int tid = threadIdx.x, wid = tid >> 6, lane = tid & 63;
    const int wq = wid >> 1, wt = wid & 1;
    const int h = blockIdx.y, b = blockIdx.z;
    const int s0 = ((int)gridDim.x - 1 - (int)blockIdx.x) * 64;  // longest-first

    const int g = lane >> 4;       // 0..3
    const int l15 = lane & 15;
    const int q8 = g << 3;
    const int swr = (l15 & 7) << 3;  // read-side XOR (ushort units)

    // Q: 32 rows (wq*32 + aq*16 + l15) x 512 L, fully resident (128 VGPR)
    bf16x8 qf[32];  // [aq*16 + c*4 + kk]
    {
        const ushort* qb = tmpb + ((long)(b * HH + h) * S + s0 + wq * 32 + l15) * LL + q8;
#pragma unroll
        for (int aq = 0; aq < 2; ++aq)
#pragma unroll
            for (int c = 0; c < 4; ++c)
#pragma unroll
                for (int kk = 0; kk < 4; ++kk)
                    qf[aq * 16 + c * 4 + kk] =
                        *(const bf16x8*)(qb + (long)aq * 16 * LL + c * 128 + kk * 32);
    }
    // pin Q fragments in registers: opaque redefinition blocks load sinking
#pragma unroll
    for (int i = 0; i < 32; ++i) asm volatile("" : "+v"(qf[i]));

    f32x4 cacc[2][4] = {};   // [aq][df] : 32q x 64d(wt half)
    f32x4 sacc[2][2] = {};   // [aq][nf] : 32q x 32t(wt half)
    float mrow[8], lrow[8];  // [aq*4+r]
#pragma unroll
    for (int i = 0; i < 8; ++i) { mrow[i] = -1e30f; lrow[i] = 0.f; }

    const int rl = tid >> 4, cc16 = tid & 15;  // K staging coords
    const int vr = tid >> 3, vc = tid & 7;     // V staging coords
    const int nfull = (s0 + PAST) / 64;
    const ushort* kbase = ckvb + (long)b * T * LL;
    const ushort* vbase = vtb + ((long)b * DV + h * DHD) * T;
    const int kcol = (cc16 ^ (rl & 7)) << 3;   // pre-swizzled K source column
    const int vcol = (vc ^ (vr & 7)) << 3;     // pre-swizzled V source column

    auto stageK = [&](int tt_, int c_, int bi) {
#pragma unroll
        for (int p = 0; p < 4; ++p)
            gll16(kbase + (long)(tt_ * 64 + p * 16 + rl) * LL + c_ * 128 + kcol,
                  &buf[bi][p * 2048 + tid * 8]);
    };
    auto stageV = [&](int tt_, int bi) {
#pragma unroll
        for (int p = 0; p < 4; ++p)
            gll16(vbase + (long)(p * 32 + vr) * T + tt_ * 64 + vcol,
                  &buf[bi][p * 2048 + tid * 8]);
    };

#define QK_CHUNK(C, BP)                                                                   \
    do {                                                                                  \
        const ushort* kb_ = &buf[BP][(wt * 32) * 128];                                    \
        __builtin_amdgcn_s_setprio(1);                                                    \
        _Pragma("unroll") for (int kk = 0; kk < 4; ++kk) {                                \
            const int ko = kk * 32 + q8;                                                  \
            _Pragma("unroll") for (int nf = 0; nf < 2; ++nf) {                            \
                bf16x8 bfr = *(const bf16x8*)(&kb_[(nf * 16 + l15) * 128 + (ko ^ swr)]);  \
                sacc[0][nf] = __builtin_amdgcn_mfma_f32_16x16x32_bf16(                    \
                    qf[(C) * 4 + kk], bfr, sacc[0][nf], 0, 0, 0);                         \
                sacc[1][nf] = __builtin_amdgcn_mfma_f32_16x16x32_bf16(                    \
                    qf[16 + (C) * 4 + kk], bfr, sacc[1][nf], 0, 0, 0);                    \
            }                                                                             \
        }                                                                                 \
        __builtin_amdgcn_s_setprio(0);                                                    \
    } while (0)

    // prologue: stream items 0,1 = K(0,0)->buf0, K(0,1)->buf1
    stageK(0, 0, 0);
    stageK(0, 1, 1);
    int bi0 = 0;

    for (int tt = 0; tt <= nfull; ++tt) {
        const bool last = (tt == nfull);
        int bA = bi0;
        int bB = bi0 + 1; if (bB >= 3) bB -= 3;
        int bC = bi0 + 2; if (bC >= 3) bC -= 3;
        PH_WAIT4();
        stageK(tt, 2, bC);
        QK_CHUNK(0, bA);
        PH_WAIT4();
        stageK(tt, 3, bA);
        QK_CHUNK(1, bB);
        PH_WAIT4();
        stageV(tt, bB);
        QK_CHUNK(2, bC);
        PH_WAIT4();
        if (!last) stageK(tt + 1, 0, bC);
        QK_CHUNK(3, bA);
        if (last) { PH_WAIT0(); } else { PH_WAIT4(); }
        if (!last) stageK(tt + 1, 1, bA);
        // ---- softmax: partial max over own t-half ----
        float pm[8];
#pragma unroll
        for (int aq = 0; aq < 2; ++aq)
#pragma unroll
            for (int r = 0; r < 4; ++r) {
                float m0 = -1e30f;
#pragma unroll
                for (int nf = 0; nf < 2; ++nf) {
                    float v = sacc[aq][nf][r];
                    if (last) {
                        int tcol = wt * 32 + nf * 16 + l15;
                        int qrl = wq * 32 + aq * 16 + g * 4 + r;
                        if (tcol > qrl) v = -1e30f;
                    }
                    sacc[aq][nf][r] = v;
                    m0 = fmaxf(m0, v);
                }
                pm[aq * 4 + r] = m0;
            }
#pragma unroll
        for (int i = 0; i < 8; ++i)
#pragma unroll
            for (int m = 1; m < 16; m <<= 1) pm[i] = fmaxf(pm[i], __shfl_xor(pm[i], m, 64));
        if (l15 == 0) {
#pragma unroll
            for (int aq = 0; aq < 2; ++aq)
#pragma unroll
                for (int r = 0; r < 4; ++r)
                    sm_m[wt][wq][aq * 16 + g * 4 + r] = pm[aq * 4 + r];
        }
        LG_BAR();
        // combined max
#pragma unroll
        for (int aq = 0; aq < 2; ++aq)
#pragma unroll
            for (int r = 0; r < 4; ++r)
                pm[aq * 4 + r] = fmaxf(pm[aq * 4 + r], sm_m[wt ^ 1][wq][aq * 16 + g * 4 + r]);
        // defer-max: both wt-partners see identical pm/mrow -> identical decision
        bool need = false;
#pragma unroll
        for (int i = 0; i < 8; ++i) need |= (pm[i] > mrow[i] + 8.0f);
        if (__any(need)) {
#pragma unroll
            for (int aq = 0; aq < 2; ++aq)
#pragma unroll
                for (int r = 0; r < 4; ++r) {
                    const int i = aq * 4 + r;
                    float mn = fmaxf(mrow[i], pm[i]);
                    float al = __expf(mrow[i] - mn);
                    mrow[i] = mn;
                    lrow[i] *= al;
#pragma unroll
                    for (int df = 0; df < 4; ++df) cacc[aq][df][r] *= al;
                }
        }
        // exp + partial sums + P write
        float ps[8] = {0.f, 0.f, 0.f, 0.f, 0.f, 0.f, 0.f, 0.f};
#pragma unroll
        for (int aq = 0; aq < 2; ++aq)
#pragma unroll
            for (int nf = 0; nf < 2; ++nf)
#pragma unroll
                for (int r = 0; r < 4; ++r) {
                    float p = __expf(sacc[aq][nf][r] - mrow[aq * 4 + r]);
                    sacc[aq][nf][r] = p;
                    ps[aq * 4 + r] += p;
                }
#pragma unroll
        for (int i = 0; i < 8; ++i)
#pragma unroll
            for (int m = 1; m < 16; m <<= 1) ps[i] += __shfl_xor(ps[i], m, 64);
#pragma unroll
        for (int aq = 0; aq < 2; ++aq)
#pragma unroll
            for (int nf = 0; nf < 2; ++nf)
#pragma unroll
                for (int r = 0; r < 4; ++r)
                    pl[wq * 32 + aq * 16 + g * 4 + r][wt * 32 + nf * 16 + l15] =
                        f2b(sacc[aq][nf][r]);
        if (l15 == 0) {
#pragma unroll
            for (int aq = 0; aq < 2; ++aq)
#pragma unroll
                for (int r = 0; r < 4; ++r)
                    sm_s[wt][wq][aq * 16 + g * 4 + r] = ps[aq * 4 + r];
        }
        LG_BAR();
#pragma unroll
        for (int aq = 0; aq < 2; ++aq)
#pragma unroll
            for (int r = 0; r < 4; ++r)
                lrow[aq * 4 + r] += ps[aq * 4 + r] + sm_s[wt ^ 1][wq][aq * 16 + g * 4 + r];
#pragma unroll
        for (int aq = 0; aq < 2; ++aq)
#pragma unroll
            for (int nf = 0; nf < 2; ++nf) sacc[aq][nf] = (f32x4){0.f, 0.f, 0.f, 0.f};
        // ---- ctx += P * V : wave's d-half, full t=64 ----
        {
            const ushort* vb_ = &buf[bB][0];
            __builtin_amdgcn_s_setprio(1);
#pragma unroll
            for (int kk = 0; kk < 2; ++kk) {
                bf16x8 pa0 = *(const bf16x8*)(&pl[wq * 32 + l15][kk * 32 + q8]);
                bf16x8 pa1 = *(const bf16x8*)(&pl[wq * 32 + 16 + l15][kk * 32 + q8]);
#pragma unroll
                for (int df = 0; df < 4; ++df) {
                    bf16x8 bv = *(const bf16x8*)(&vb_[(wt * 64 + df * 16 + l15) * 64 +
                                                      ((kk * 32 + q8) ^ swr)]);
                    cacc[0][df] = __builtin_amdgcn_mfma_f32_16x16x32_bf16(pa0, bv, cacc[0][df], 0, 0, 0);
                    cacc[1][df] = __builtin_amdgcn_mfma_f32_16x16x32_bf16(pa1, bv, cacc[1][df], 0, 0, 0);
                }
            }
            __builtin_amdgcn_s_setprio(0);
        }
        bi0 = bC;
    }
    // ---- epilogue: wave's 32 q-rows x 64 d-half ----
#pragma unroll
    for (int aq = 0; aq < 2; ++aq)
#pragma unroll
        for (int r = 0; r < 4; ++r) {
            float inv = 1.0f / lrow[aq * 4 + r];
            const long row = (long)b * S + s0 + wq * 32 + aq * 16 + g * 4 + r;
            const int d = h * DHD + wt * 64 + l15;
#pragma unroll
            for (int df = 0; df < 4; ++df)
                ctxb[row * DV + d + df * 16] = f2b(cacc[aq][df][r] * inv);
        }
}

extern "C" void kernel_launch(void* const* d_in, const int* in_sizes, int n_in,
                              void* d_out, int out_size, void* d_ws, size_t ws_size,
                              hipStream_t stream) {
    const float* x = (const float*)d_in[0];
    const float* kv = (const float*)d_in[1];
    const float* Wq = (const float*)d_in[2];
    const float* Wdkv = (const float*)d_in[3];
    const float* Wuk = (const float*)d_in[4];
    const float* Wuv = (const float*)d_in[5];
    const float* Wo = (const float*)d_in[6];
    const float* lng = (const float*)d_in[7];
    const float* lnbt = (const float*)d_in[8];
    const int S = in_sizes[0] / (BB * DV);     // 2048
    const int PAST = in_sizes[1] / (BB * LL);  // 2048
    const int T = S + PAST;                    // 4096

    float* out_p = (float*)d_out;                       // [B,S,D] f32
    float* ckv_out = out_p + (size_t)BB * S * DV;       // [B,T,L] f32

    char* w = (char*)d_ws;
    auto take = [&](size_t bytes) { char* p = w; w += (bytes + 255) & ~(size_t)255; return p; };
    ushort* xb    = (ushort*)take((size_t)BB * S * DV * 2);
    ushort* Wqb   = (ushort*)take((size_t)DV * DV * 2);
    ushort* WukT  = (ushort*)take((size_t)DV * LL * 2);   // [L][D]
    ushort* Wdkvb = (ushort*)take((size_t)LL * DV * 2);
    ushort* Wuvb  = (ushort*)take((size_t)DV * LL * 2);
    ushort* Wob   = (ushort*)take((size_t)DV * DV * 2);
    ushort* absT  = (ushort*)take((size_t)LL * DV * 2);   // [L][D] = absorbed^T
    float*  cpre  = (float*)take((size_t)BB * S * LL * 4);
    ushort* ckvb  = (ushort*)take((size_t)BB * T * LL * 2);
    ushort* vtb   = (ushort*)take((size_t)BB * DV * T * 2); // [B][D][T]
    ushort* tmpb  = (ushort*)take((size_t)BB * HH * S * LL * 2);
    ushort* ctxb  = (ushort*)take((size_t)BB * S * DV * 2);

    auto cvt = [&](const float* in, ushort* op, long n) {
        long nb = (n / 4 + 255) / 256;
        if (nb > 2048) nb = 2048;
        cvt_k<<<dim3((unsigned)nb), dim3(256), 0, stream>>>(in, op, n);
    };
    cvt(x, xb, (long)BB * S * DV);
    cvt(Wq, Wqb, (long)DV * DV);
    cvt(Wdkv, Wdkvb, (long)LL * DV);
    cvt(Wuv, Wuvb, (long)DV * LL);
    cvt(Wo, Wob, (long)DV * DV);
    transpose_cvt_k<<<dim3(LL / 64, DV / 64), dim3(256), 0, stream>>>(Wuk, WukT, DV, LL);
    kvcopy_k<<<dim3(2048), dim3(256), 0, stream>>>(kv, ckv_out, ckvb, PAST, T);

    // absorbed^T[l,i] = sum_k WukT[l,k] * Wq[i,k]
    gemm_nt<true><<<dim3(LL / 128, DV / 128, 1), dim3(256), 0, stream>>>(
        WukT, Wqb, absT, DV, DV, DV, DV, 0, 0, 0, 0, 0, 0, 1, 1.0f);
    // c_pre = x * Wdkv^T  (f32)
    gemm_nt<false><<<dim3(BB * S / 128, LL / 128, 1), dim3(256), 0, stream>>>(
        xb, Wdkvb, cpre, DV, DV, DV, LL, 0, 0, 0, 0, 0, 0, 1, 1.0f);
    ln_k<<<dim3(BB * S / 4), dim3(256), 0, stream>>>(cpre, lng, lnbt, ckv_out, ckvb, S, PAST, T);
    // Vt[b] = Wuv * ckv[b]^T : [D][T] bf16
    gemm_nt<true><<<dim3(DV / 128, T / 128, BB), dim3(256), 0, stream>>>(
        Wuvb, ckvb, vtb, LL, LL, LL, T, 0, 0, (long)T * LL, 0, (long)DV * T, 0, 1, 1.0f);
    // tmp[b,h] = x_h * absorbed_h^T, pre-scaled by 1/sqrt(dh)
    gemm_nt<true><<<dim3(S / 128, LL / 128, BB * HH), dim3(256), 0, stream>>>(
        xb, absT, tmpb, DHD, DV, DV, LL,
        (long)S * DV, DHD, 0, DHD, (long)HH * S * LL, (long)S * LL, HH,
        0.08838834764831845f);
    // attention
    attn_k<<<dim3(S / 64, HH, BB), dim3(256), 0, stream>>>(tmpb, ckvb, vtb, ctxb, S, T, PAST);
    // out = ctx * Wo^T (f32)
    gemm_nt<false><<<dim3(BB * S / 128, DV / 128, 1), dim3(256), 0, stream>>>(
        ctxb, Wob, out_p, DV, DV, DV, DV, 0, 0, 0, 0, 0, 0, 1, 1.0f);
}

// Round 9
// 521.599 us; speedup vs baseline: 2.6228x; 1.7077x over previous
//
#include <hip/hip_runtime.h>
#include <cstdint>

#define DV 2048
#define HH 16
#define DHD 128
#define LL 512
#define BB 2

typedef __attribute__((ext_vector_type(8))) short bf16x8;
typedef __attribute__((ext_vector_type(4))) float f32x4;
typedef __attribute__((ext_vector_type(4))) int i32x4;

typedef __attribute__((address_space(1))) const void* gas_cp;
typedef __attribute__((address_space(3))) void* las_p;

__device__ __forceinline__ void gll16(const void* g, void* l) {
    __builtin_amdgcn_global_load_lds((gas_cp)g, (las_p)l, 16, 0, 0);
}

__device__ __forceinline__ unsigned short f2b(float f) {
    union { float f; unsigned int u; } v; v.f = f;
    unsigned int u = v.u;
    return (unsigned short)((u + 0x7FFFu + ((u >> 16) & 1u)) >> 16);
}

// ---------------- elementwise f32 -> bf16 ----------------
__global__ void cvt_k(const float* __restrict__ in, ushort* __restrict__ out, long n) {
    long stride = (long)gridDim.x * blockDim.x * 4;
    for (long i = ((long)blockIdx.x * blockDim.x + threadIdx.x) * 4; i < n; i += stride) {
        float4 f = *(const float4*)(in + i);
        *(ushort4*)(out + i) = make_ushort4(f2b(f.x), f2b(f.y), f2b(f.z), f2b(f.w));
    }
}

// ---------------- transpose + convert: out[c][r] = in[r][c] ----------------
__global__ void transpose_cvt_k(const float* __restrict__ in, ushort* __restrict__ outp,
                                int R, int C) {
    __shared__ float tile[64][65];
    int c0 = blockIdx.x * 64, r0 = blockIdx.y * 64;
    int tx = threadIdx.x & 63, ty = threadIdx.x >> 6;
#pragma unroll
    for (int p = 0; p < 16; ++p)
        tile[ty + p * 4][tx] = in[(long)(r0 + ty + p * 4) * C + c0 + tx];
    __syncthreads();
#pragma unroll
    for (int p = 0; p < 16; ++p)
        outp[(long)(c0 + ty + p * 4) * R + r0 + tx] = f2b(tile[tx][ty + p * 4]);
}

// ---------------- kv_cache -> c_kv out (f32) + bf16 copy ----------------
__global__ void kvcopy_k(const float* __restrict__ kv, float* __restrict__ cko,
                         ushort* __restrict__ ckb, int PAST, int T) {
    long n = (long)BB * PAST * LL;
    long pl2 = (long)PAST * LL;
    long stride = (long)gridDim.x * blockDim.x * 4;
    for (long i = ((long)blockIdx.x * blockDim.x + threadIdx.x) * 4; i < n; i += stride) {
        float4 f = *(const float4*)(kv + i);
        long b = i / pl2, wloc = i - b * pl2;
        long o = b * (long)T * LL + wloc;
        *(float4*)(cko + o) = f;
        *(ushort4*)(ckb + o) = make_ushort4(f2b(f.x), f2b(f.y), f2b(f.z), f2b(f.w));
    }
}

// ---------------- LayerNorm over L=512, one wave per row ----------------
__global__ __launch_bounds__(256) void ln_k(const float* __restrict__ cpre,
                                            const float* __restrict__ g, const float* __restrict__ be,
                                            float* __restrict__ cko, ushort* __restrict__ ckb,
                                            int S, int PAST, int T) {
    int wid = threadIdx.x >> 6, lane = threadIdx.x & 63;
    int row = blockIdx.x * 4 + wid;
    int b = row / S, s = row - b * S;
    const float* xr = cpre + (long)row * LL + lane * 8;
    float4 v0 = *(const float4*)xr;
    float4 v1 = *(const float4*)(xr + 4);
    float sum = v0.x + v0.y + v0.z + v0.w + v1.x + v1.y + v1.z + v1.w;
    float sq = v0.x * v0.x + v0.y * v0.y + v0.z * v0.z + v0.w * v0.w +
               v1.x * v1.x + v1.y * v1.y + v1.z * v1.z + v1.w * v1.w;
#pragma unroll
    for (int m = 1; m < 64; m <<= 1) { sum += __shfl_xor(sum, m, 64); sq += __shfl_xor(sq, m, 64); }
    float mu = sum * (1.0f / LL);
    float var = sq * (1.0f / LL) - mu * mu;
    float rstd = rsqrtf(var + 1e-5f);
    const float* gp = g + lane * 8;
    const float* bp = be + lane * 8;
    float4 g0 = *(const float4*)gp, g1 = *(const float4*)(gp + 4);
    float4 b0 = *(const float4*)bp, b1 = *(const float4*)(bp + 4);
    float y0 = (v0.x - mu) * rstd * g0.x + b0.x;
    float y1 = (v0.y - mu) * rstd * g0.y + b0.y;
    float y2 = (v0.z - mu) * rstd * g0.z + b0.z;
    float y3 = (v0.w - mu) * rstd * g0.w + b0.w;
    float y4 = (v1.x - mu) * rstd * g1.x + b1.x;
    float y5 = (v1.y - mu) * rstd * g1.y + b1.y;
    float y6 = (v1.z - mu) * rstd * g1.z + b1.z;
    float y7 = (v1.w - mu) * rstd * g1.w + b1.w;
    long o = ((long)b * T + PAST + s) * LL + lane * 8;
    *(float4*)(cko + o) = make_float4(y0, y1, y2, y3);
    *(float4*)(cko + o + 4) = make_float4(y4, y5, y6, y7);
    *(ushort4*)(ckb + o) = make_ushort4(f2b(y0), f2b(y1), f2b(y2), f2b(y3));
    *(ushort4*)(ckb + o + 4) = make_ushort4(f2b(y4), f2b(y5), f2b(y6), f2b(y7));
}

// ---------------- generic NT GEMM: C[M,N] = cscale * A[M,K] * B[N,K]^T ----------------
template <bool OUT_BF16>
__global__ __launch_bounds__(256, 2) void gemm_nt(const ushort* __restrict__ A,
                                                  const ushort* __restrict__ B,
                                                  void* __restrict__ Cv,
                                                  int K, int lda, int ldb, int ldc,
                                                  long aHi, long aLo, long bHi, long bLo,
                                                  long cHi, long cLo, int zdiv, float cscale) {
    __shared__ __align__(16) ushort Asm[128 * 72];
    __shared__ __align__(16) ushort Bsm[128 * 72];
    const int tid = threadIdx.x, wid = tid >> 6, lane = tid & 63;
    const int z = blockIdx.z, zh = z / zdiv, zl = z % zdiv;
    A += zh * aHi + zl * aLo;
    B += zh * bHi + zl * bLo;
    const long cOff = zh * cHi + zl * cLo;
    const int m0 = blockIdx.x * 128, n0 = blockIdx.y * 128;
    const int wm = (wid >> 1) * 64, wn = (wid & 1) * 64;
    f32x4 acc[4][4] = {};
    const int l8 = lane & 7;
    const int rowA = wid * 8 + (lane >> 3);
    const ushort* Ag = A + (long)(m0 + rowA) * lda + l8 * 8;
    const ushort* Bg = B + (long)(n0 + rowA) * ldb + l8 * 8;

    i32x4 ra[4], rb[4];
#pragma unroll
    for (int p = 0; p < 4; ++p) {
        ra[p] = *(const i32x4*)(Ag + (long)p * 32 * lda);
        rb[p] = *(const i32x4*)(Bg + (long)p * 32 * ldb);
    }
    for (int kt = 0; kt < K; kt += 64) {
        __syncthreads();
#pragma unroll
        for (int p = 0; p < 4; ++p) {
            *(i32x4*)(Asm + (p * 32 + rowA) * 72 + l8 * 8) = ra[p];
            *(i32x4*)(Bsm + (p * 32 + rowA) * 72 + l8 * 8) = rb[p];
        }
        __syncthreads();
        if (kt + 64 < K) {
#pragma unroll
            for (int p = 0; p < 4; ++p) {
                ra[p] = *(const i32x4*)(Ag + (long)p * 32 * lda + kt + 64);
                rb[p] = *(const i32x4*)(Bg + (long)p * 32 * ldb + kt + 64);
            }
        }
#pragma unroll
        for (int kk = 0; kk < 2; ++kk) {
            const int ko = kk * 32 + ((lane >> 4) << 3);
            bf16x8 af[4], bf[4];
#pragma unroll
            for (int i = 0; i < 4; ++i)
                af[i] = *(const bf16x8*)(Asm + (wm + i * 16 + (lane & 15)) * 72 + ko);
#pragma unroll
            for (int j = 0; j < 4; ++j)
                bf[j] = *(const bf16x8*)(Bsm + (wn + j * 16 + (lane & 15)) * 72 + ko);
#pragma unroll
            for (int i = 0; i < 4; ++i)
#pragma unroll
                for (int j = 0; j < 4; ++j)
                    acc[i][j] = __builtin_amdgcn_mfma_f32_16x16x32_bf16(af[i], bf[j], acc[i][j], 0, 0, 0);
        }
        __syncthreads();
    }
    const int cr = (lane >> 4) * 4, cc = lane & 15;
#pragma unroll
    for (int i = 0; i < 4; ++i) {
#pragma unroll
        for (int r = 0; r < 4; ++r) {
            const long row = m0 + wm + i * 16 + cr + r;
#pragma unroll
            for (int j = 0; j < 4; ++j) {
                const long col = n0 + wn + j * 16 + cc;
                if (OUT_BF16)
                    ((ushort*)Cv)[cOff + row * ldc + col] = f2b(acc[i][j][r] * cscale);
                else
                    ((float*)Cv)[cOff + row * ldc + col] = acc[i][j][r] * cscale;
            }
        }
    }
}

// ---------------- flash attention (round 9: khat-decompressed, d=128) ----------------
// scores_h = x_h · khat_h^T where khat = c_kv @ absorbed^T (absorbed = Wq@Wuk,
// scale folded). Q = per-head slice of x (bf16). V transposed [b][d][t].
// r5 skeleton: 4 waves x 16 q-rows, wave-local softmax, 3 rotating 16 KB LDS
// buffers, stream [K(tt), V(tt)] = 2 phases/tile, counted vmcnt(4),
// gll16 + XOR swizzle.
#define PH_WAIT4()                                               \
    do {                                                         \
        asm volatile("s_waitcnt vmcnt(4) lgkmcnt(0)" ::: "memory"); \
        __builtin_amdgcn_s_barrier();                            \
    } while (0)
#define PH_WAIT0()                                               \
    do {                                                         \
        asm volatile("s_waitcnt vmcnt(0) lgkmcnt(0)" ::: "memory"); \
        __builtin_amdgcn_s_barrier();                            \
    } while (0)

__global__ __launch_bounds__(256) void attn_k(const ushort* __restrict__ qbf,
                                              const ushort* __restrict__ ktb,
                                              const ushort* __restrict__ vtb,
                                              ushort* __restrict__ ctxb,
                                              int S, int T, int PAST) {
    __shared__ __align__(16) ushort buf[3][8192];  // K view: [64t][128d]; V view: [128d][64t]
    __shared__ __align__(16) ushort pl[4][16][72]; // per-wave P [q16][t64+8pad]
    const int tid = threadIdx.x, wid = tid >> 6, lane = tid & 63;
    const int h = blockIdx.y, b = blockIdx.z;
    const int s0 = ((int)gridDim.x - 1 - (int)blockIdx.x) * 64;  // longest-first

    const int g = lane >> 4;
    const int l15 = lane & 15;
    const int q8 = g << 3;
    const int swr = (l15 & 7) << 3;  // read-side XOR (ushort units)

    // Q fragments: 16 rows x 128 d = per-head slice of x (scale folded in khat)
    bf16x8 qf[4];
    {
        const ushort* qb = qbf + ((long)b * S + s0 + wid * 16 + l15) * DV + h * DHD + q8;
#pragma unroll
        for (int kk = 0; kk < 4; ++kk) qf[kk] = *(const bf16x8*)(qb + kk * 32);
    }
    f32x4 cacc[8] = {};
    f32x4 sacc[4] = {};
    float mrow[4] = {-1e30f, -1e30f, -1e30f, -1e30f};
    float lrow[4] = {0.f, 0.f, 0.f, 0.f};
    const int rl = tid >> 4, cc16 = tid & 15;  // K staging coords (16 rows x 16 lanes)
    const int vr = tid >> 3, vc = tid & 7;     // V staging coords (32 rows x 8 lanes)
    const int nfull = (s0 + PAST) / 64;
    const ushort* kbase = ktb + (long)b * T * DV + h * DHD;
    const ushort* vbase = vtb + ((long)b * DV + h * DHD) * T;
    const int kcol = (cc16 ^ (rl & 7)) << 3;   // pre-swizzled K source column (ushorts)
    const int vcol = (vc ^ (vr & 7)) << 3;     // pre-swizzled V source column (ushorts)

    auto stageK = [&](int tt_, int bi) {
#pragma unroll
        for (int p = 0; p < 4; ++p)
            gll16(kbase + (long)(tt_ * 64 + p * 16 + rl) * DV + kcol,
                  &buf[bi][p * 2048 + tid * 8]);
    };
    auto stageV = [&](int tt_, int bi) {
#pragma unroll
        for (int p = 0; p < 4; ++p)
            gll16(vbase + (long)(p * 32 + vr) * T + tt_ * 64 + vcol,
                  &buf[bi][p * 2048 + tid * 8]);
    };

    // prologue: K(0)->buf0, V(0)->buf1
    stageK(0, 0);
    stageV(0, 1);
    int bi0 = 0;

    for (int tt = 0; tt <= nfull; ++tt) {
        const bool last = (tt == nfull);
        int bA = bi0;
        int bB = bi0 + 1; if (bB >= 3) bB -= 3;
        int bC = bi0 + 2; if (bC >= 3) bC -= 3;
        // ---- phase A: K(tt) ready in bA; stage K(tt+1)->bC; QK ----
        PH_WAIT4();
        if (!last) stageK(tt + 1, bC);
        {
            const ushort* kb_ = &buf[bA][0];
            __builtin_amdgcn_s_setprio(1);
#pragma unroll
            for (int kk = 0; kk < 4; ++kk) {
                const int ko = kk * 32 + q8;
#pragma unroll
                for (int nf = 0; nf < 4; ++nf) {
                    bf16x8 bfr = *(const bf16x8*)(&kb_[(nf * 16 + l15) * 128 + (ko ^ swr)]);
                    sacc[nf] = __builtin_amdgcn_mfma_f32_16x16x32_bf16(qf[kk], bfr, sacc[nf], 0, 0, 0);
                }
            }
            __builtin_amdgcn_s_setprio(0);
        }
        // ---- phase B: V(tt) ready in bB; stage V(tt+1)->bA; softmax+PV ----
        if (last) { PH_WAIT0(); } else { PH_WAIT4(); }
        if (!last) stageV(tt + 1, bA);
        // online softmax (scale pre-folded)
        float pm[4] = {-1e30f, -1e30f, -1e30f, -1e30f};
#pragma unroll
        for (int nf = 0; nf < 4; ++nf)
#pragma unroll
            for (int r = 0; r < 4; ++r) {
                float v = sacc[nf][r];
                if (last) {
                    int tcol = nf * 16 + l15;
                    int qrl = wid * 16 + (g << 2) + r;
                    if (tcol > qrl) v = -1e30f;
                }
                sacc[nf][r] = v;
                pm[r] = fmaxf(pm[r], v);
            }
#pragma unroll
        for (int r = 0; r < 4; ++r)
#pragma unroll
            for (int m = 1; m < 16; m <<= 1) pm[r] = fmaxf(pm[r], __shfl_xor(pm[r], m, 64));
        bool need = false;
#pragma unroll
        for (int r = 0; r < 4; ++r) need |= (pm[r] > mrow[r] + 8.0f);
        if (__any(need)) {
#pragma unroll
            for (int r = 0; r < 4; ++r) {
                float mn = fmaxf(mrow[r], pm[r]);
                float al = __expf(mrow[r] - mn);
                mrow[r] = mn;
                lrow[r] *= al;
#pragma unroll
                for (int df = 0; df < 8; ++df) cacc[df][r] *= al;
            }
        }
        float ps[4] = {0.f, 0.f, 0.f, 0.f};
#pragma unroll
        for (int nf = 0; nf < 4; ++nf)
#pragma unroll
            for (int r = 0; r < 4; ++r) {
                float p = __expf(sacc[nf][r] - mrow[r]);
                sacc[nf][r] = p;
                ps[r] += p;
            }
#pragma unroll
        for (int r = 0; r < 4; ++r) {
#pragma unroll
            for (int m = 1; m < 16; m <<= 1) ps[r] += __shfl_xor(ps[r], m, 64);
            lrow[r] += ps[r];
        }
        // P -> wave-private LDS
#pragma unroll
        for (int nf = 0; nf < 4; ++nf)
#pragma unroll
            for (int r = 0; r < 4; ++r)
                pl[wid][(g << 2) + r][nf * 16 + l15] = f2b(sacc[nf][r]);
#pragma unroll
        for (int nf = 0; nf < 4; ++nf) sacc[nf] = (f32x4){0.f, 0.f, 0.f, 0.f};
        // ctx += P * V from bB (V rows d = df*16+l15, swizzled cols)
        {
            const ushort* vb_ = &buf[bB][0];
            __builtin_amdgcn_s_setprio(1);
#pragma unroll
            for (int kk = 0; kk < 2; ++kk) {
                bf16x8 a = *(const bf16x8*)(&pl[wid][l15][kk * 32 + q8]);
#pragma unroll
                for (int df = 0; df < 8; ++df) {
                    bf16x8 bv = *(const bf16x8*)(&vb_[(df * 16 + l15) * 64 + ((kk * 32 + q8) ^ swr)]);
                    cacc[df] = __builtin_amdgcn_mfma_f32_16x16x32_bf16(a, bv, cacc[df], 0, 0, 0);
                }
            }
            __builtin_amdgcn_s_setprio(0);
        }
        bi0 = bC;
    }
    // ---- epilogue ----
    const long rbase = (long)b * S + s0 + wid * 16 + (g << 2);
#pragma unroll
    for (int r = 0; r < 4; ++r) {
        float inv = 1.0f / lrow[r];
        const int d = h * DHD + l15;
#pragma unroll
        for (int df = 0; df < 8; ++df)
            ctxb[(rbase + r) * DV + d + df * 16] = f2b(cacc[df][r] * inv);
    }
}

extern "C" void kernel_launch(void* const* d_in, const int* in_sizes, int n_in,
                              void* d_out, int out_size, void* d_ws, size_t ws_size,
                              hipStream_t stream) {
    const float* x = (const float*)d_in[0];
    const float* kv = (const float*)d_in[1];
    const float* Wq = (const float*)d_in[2];
    const float* Wdkv = (const float*)d_in[3];
    const float* Wuk = (const float*)d_in[4];
    const float* Wuv = (const float*)d_in[5];
    const float* Wo = (const float*)d_in[6];
    const float* lng = (const float*)d_in[7];
    const float* lnbt = (const float*)d_in[8];
    const int S = in_sizes[0] / (BB * DV);     // 2048
    const int PAST = in_sizes[1] / (BB * LL);  // 2048
    const int T = S + PAST;                    // 4096

    float* out_p = (float*)d_out;                       // [B,S,D] f32
    float* ckv_out = out_p + (size_t)BB * S * DV;       // [B,T,L] f32

    char* w = (char*)d_ws;
    auto take = [&](size_t bytes) { char* p = w; w += (bytes + 255) & ~(size_t)255; return p; };
    ushort* xb    = (ushort*)take((size_t)BB * S * DV * 2);
    ushort* Wqb   = (ushort*)take((size_t)DV * DV * 2);
    ushort* WukT  = (ushort*)take((size_t)DV * LL * 2);   // [L][D] = Wuk^T
    ushort* Wdkvb = (ushort*)take((size_t)LL * DV * 2);
    ushort* Wuvb  = (ushort*)take((size_t)DV * LL * 2);
    ushort* Wob   = (ushort*)take((size_t)DV * DV * 2);
    ushort* absb  = (ushort*)take((size_t)DV * LL * 2);   // [D][L] = Wq@Wuk (scaled)
    float*  cpre  = (float*)take((size_t)BB * S * LL * 4);
    ushort* ckvb  = (ushort*)take((size_t)BB * T * LL * 2);
    ushort* vtb   = (ushort*)take((size_t)BB * DV * T * 2);  // [B][D][T]
    ushort* ktb   = (ushort*)take((size_t)BB * T * DV * 2);  // [B][T][D] khat
    ushort* ctxb  = (ushort*)take((size_t)BB * S * DV * 2);

    auto cvt = [&](const float* in, ushort* op, long n) {
        long nb = (n / 4 + 255) / 256;
        if (nb > 2048) nb = 2048;
        cvt_k<<<dim3((unsigned)nb), dim3(256), 0, stream>>>(in, op, n);
    };
    cvt(x, xb, (long)BB * S * DV);
    cvt(Wq, Wqb, (long)DV * DV);
    cvt(Wdkv, Wdkvb, (long)LL * DV);
    cvt(Wuv, Wuvb, (long)DV * LL);
    cvt(Wo, Wob, (long)DV * DV);
    transpose_cvt_k<<<dim3(LL / 64, DV / 64), dim3(256), 0, stream>>>(Wuk, WukT, DV, LL);
    kvcopy_k<<<dim3(2048), dim3(256), 0, stream>>>(kv, ckv_out, ckvb, PAST, T);

    // absorbed[j,l] = sum_i Wq[j,i]*Wuk[i,l], scaled by 1/sqrt(dh) -> [D][L]
    gemm_nt<true><<<dim3(DV / 128, LL / 128, 1), dim3(256), 0, stream>>>(
        Wqb, WukT, absb, DV, DV, DV, LL, 0, 0, 0, 0, 0, 0, 1, 0.08838834764831845f);
    // c_pre = x * Wdkv^T  (f32)
    gemm_nt<false><<<dim3(BB * S / 128, LL / 128, 1), dim3(256), 0, stream>>>(
        xb, Wdkvb, cpre, DV, DV, DV, LL, 0, 0, 0, 0, 0, 0, 1, 1.0f);
    ln_k<<<dim3(BB * S / 4), dim3(256), 0, stream>>>(cpre, lng, lnbt, ckv_out, ckvb, S, PAST, T);
    // Vt[b] = Wuv * ckv[b]^T : [D][T] bf16
    gemm_nt<true><<<dim3(DV / 128, T / 128, BB), dim3(256), 0, stream>>>(
        Wuvb, ckvb, vtb, LL, LL, LL, T, 0, 0, (long)T * LL, 0, (long)DV * T, 0, 1, 1.0f);
    // khat[b] = ckv[b] @ absorbed^T : [T][D] bf16
    gemm_nt<true><<<dim3(T / 128, DV / 128, BB), dim3(256), 0, stream>>>(
        ckvb, absb, ktb, LL, LL, LL, DV, (long)T * LL, 0, 0, 0, (long)T * DV, 0, 1, 1.0f);
    // attention (d=128 MHA; Q = per-head slice of x)
    attn_k<<<dim3(S / 64, HH, BB), dim3(256), 0, stream>>>(xb, ktb, vtb, ctxb, S, T, PAST);
    // out = ctx * Wo^T (f32)
    gemm_nt<false><<<dim3(BB * S / 128, DV / 128, 1), dim3(256), 0, stream>>>(
        ctxb, Wob, out_p, DV, DV, DV, DV, 0, 0, 0, 0, 0, 0, 1, 1.0f);
}

// Round 10
// 388.083 us; speedup vs baseline: 3.5251x; 1.3440x over previous
//
#include <hip/hip_runtime.h>
#include <cstdint>

#define DV 2048
#define HH 16
#define DHD 128
#define LL 512
#define BB 2

typedef __attribute__((ext_vector_type(8))) short bf16x8;
typedef __attribute__((ext_vector_type(4))) float f32x4;
typedef __attribute__((ext_vector_type(4))) int i32x4;

typedef __attribute__((address_space(1))) const void* gas_cp;
typedef __attribute__((address_space(3))) void* las_p;

__device__ __forceinline__ void gll16(const void* g, void* l) {
    __builtin_amdgcn_global_load_lds((gas_cp)g, (las_p)l, 16, 0, 0);
}

__device__ __forceinline__ unsigned short f2b(float f) {
    union { float f; unsigned int u; } v; v.f = f;
    unsigned int u = v.u;
    return (unsigned short)((u + 0x7FFFu + ((u >> 16) & 1u)) >> 16);
}

// ---------------- elementwise f32 -> bf16 ----------------
__global__ void cvt_k(const float* __restrict__ in, ushort* __restrict__ out, long n) {
    long stride = (long)gridDim.x * blockDim.x * 4;
    for (long i = ((long)blockIdx.x * blockDim.x + threadIdx.x) * 4; i < n; i += stride) {
        float4 f = *(const float4*)(in + i);
        *(ushort4*)(out + i) = make_ushort4(f2b(f.x), f2b(f.y), f2b(f.z), f2b(f.w));
    }
}

// ---------------- transpose + convert: out[c][r] = in[r][c] ----------------
__global__ void transpose_cvt_k(const float* __restrict__ in, ushort* __restrict__ outp,
                                int R, int C) {
    __shared__ float tile[64][65];
    int c0 = blockIdx.x * 64, r0 = blockIdx.y * 64;
    int tx = threadIdx.x & 63, ty = threadIdx.x >> 6;
#pragma unroll
    for (int p = 0; p < 16; ++p)
        tile[ty + p * 4][tx] = in[(long)(r0 + ty + p * 4) * C + c0 + tx];
    __syncthreads();
#pragma unroll
    for (int p = 0; p < 16; ++p)
        outp[(long)(c0 + ty + p * 4) * R + r0 + tx] = f2b(tile[tx][ty + p * 4]);
}

// ---------------- kv_cache -> c_kv out (f32) + bf16 copy ----------------
__global__ void kvcopy_k(const float* __restrict__ kv, float* __restrict__ cko,
                         ushort* __restrict__ ckb, int PAST, int T) {
    long n = (long)BB * PAST * LL;
    long pl2 = (long)PAST * LL;
    long stride = (long)gridDim.x * blockDim.x * 4;
    for (long i = ((long)blockIdx.x * blockDim.x + threadIdx.x) * 4; i < n; i += stride) {
        float4 f = *(const float4*)(kv + i);
        long b = i / pl2, wloc = i - b * pl2;
        long o = b * (long)T * LL + wloc;
        *(float4*)(cko + o) = f;
        *(ushort4*)(ckb + o) = make_ushort4(f2b(f.x), f2b(f.y), f2b(f.z), f2b(f.w));
    }
}

// ---------------- LayerNorm over L=512, one wave per row ----------------
__global__ __launch_bounds__(256) void ln_k(const float* __restrict__ cpre,
                                            const float* __restrict__ g, const float* __restrict__ be,
                                            float* __restrict__ cko, ushort* __restrict__ ckb,
                                            int S, int PAST, int T) {
    int wid = threadIdx.x >> 6, lane = threadIdx.x & 63;
    int row = blockIdx.x * 4 + wid;
    int b = row / S, s = row - b * S;
    const float* xr = cpre + (long)row * LL + lane * 8;
    float4 v0 = *(const float4*)xr;
    float4 v1 = *(const float4*)(xr + 4);
    float sum = v0.x + v0.y + v0.z + v0.w + v1.x + v1.y + v1.z + v1.w;
    float sq = v0.x * v0.x + v0.y * v0.y + v0.z * v0.z + v0.w * v0.w +
               v1.x * v1.x + v1.y * v1.y + v1.z * v1.z + v1.w * v1.w;
#pragma unroll
    for (int m = 1; m < 64; m <<= 1) { sum += __shfl_xor(sum, m, 64); sq += __shfl_xor(sq, m, 64); }
    float mu = sum * (1.0f / LL);
    float var = sq * (1.0f / LL) - mu * mu;
    float rstd = rsqrtf(var + 1e-5f);
    const float* gp = g + lane * 8;
    const float* bp = be + lane * 8;
    float4 g0 = *(const float4*)gp, g1 = *(const float4*)(gp + 4);
    float4 b0 = *(const float4*)bp, b1 = *(const float4*)(bp + 4);
    float y0 = (v0.x - mu) * rstd * g0.x + b0.x;
    float y1 = (v0.y - mu) * rstd * g0.y + b0.y;
    float y2 = (v0.z - mu) * rstd * g0.z + b0.z;
    float y3 = (v0.w - mu) * rstd * g0.w + b0.w;
    float y4 = (v1.x - mu) * rstd * g1.x + b1.x;
    float y5 = (v1.y - mu) * rstd * g1.y + b1.y;
    float y6 = (v1.z - mu) * rstd * g1.z + b1.z;
    float y7 = (v1.w - mu) * rstd * g1.w + b1.w;
    long o = ((long)b * T + PAST + s) * LL + lane * 8;
    *(float4*)(cko + o) = make_float4(y0, y1, y2, y3);
    *(float4*)(cko + o + 4) = make_float4(y4, y5, y6, y7);
    *(ushort4*)(ckb + o) = make_ushort4(f2b(y0), f2b(y1), f2b(y2), f2b(y3));
    *(ushort4*)(ckb + o + 4) = make_ushort4(f2b(y4), f2b(y5), f2b(y6), f2b(y7));
}

// ---------------- generic NT GEMM: C[M,N] = cscale * A[M,K] * B[N,K]^T ----------------
template <bool OUT_BF16>
__global__ __launch_bounds__(256, 2) void gemm_nt(const ushort* __restrict__ A,
                                                  const ushort* __restrict__ B,
                                                  void* __restrict__ Cv,
                                                  int K, int lda, int ldb, int ldc,
                                                  long aHi, long aLo, long bHi, long bLo,
                                                  long cHi, long cLo, int zdiv, float cscale) {
    __shared__ __align__(16) ushort Asm[128 * 72];
    __shared__ __align__(16) ushort Bsm[128 * 72];
    const int tid = threadIdx.x, wid = tid >> 6, lane = tid & 63;
    const int z = blockIdx.z, zh = z / zdiv, zl = z % zdiv;
    A += zh * aHi + zl * aLo;
    B += zh * bHi + zl * bLo;
    const long cOff = zh * cHi + zl * cLo;
    const int m0 = blockIdx.x * 128, n0 = blockIdx.y * 128;
    const int wm = (wid >> 1) * 64, wn = (wid & 1) * 64;
    f32x4 acc[4][4] = {};
    const int l8 = lane & 7;
    const int rowA = wid * 8 + (lane >> 3);
    const ushort* Ag = A + (long)(m0 + rowA) * lda + l8 * 8;
    const ushort* Bg = B + (long)(n0 + rowA) * ldb + l8 * 8;

    i32x4 ra[4], rb[4];
#pragma unroll
    for (int p = 0; p < 4; ++p) {
        ra[p] = *(const i32x4*)(Ag + (long)p * 32 * lda);
        rb[p] = *(const i32x4*)(Bg + (long)p * 32 * ldb);
    }
    for (int kt = 0; kt < K; kt += 64) {
        __syncthreads();
#pragma unroll
        for (int p = 0; p < 4; ++p) {
            *(i32x4*)(Asm + (p * 32 + rowA) * 72 + l8 * 8) = ra[p];
            *(i32x4*)(Bsm + (p * 32 + rowA) * 72 + l8 * 8) = rb[p];
        }
        __syncthreads();
        if (kt + 64 < K) {
#pragma unroll
            for (int p = 0; p < 4; ++p) {
                ra[p] = *(const i32x4*)(Ag + (long)p * 32 * lda + kt + 64);
                rb[p] = *(const i32x4*)(Bg + (long)p * 32 * ldb + kt + 64);
            }
        }
#pragma unroll
        for (int kk = 0; kk < 2; ++kk) {
            const int ko = kk * 32 + ((lane >> 4) << 3);
            bf16x8 af[4], bf[4];
#pragma unroll
            for (int i = 0; i < 4; ++i)
                af[i] = *(const bf16x8*)(Asm + (wm + i * 16 + (lane & 15)) * 72 + ko);
#pragma unroll
            for (int j = 0; j < 4; ++j)
                bf[j] = *(const bf16x8*)(Bsm + (wn + j * 16 + (lane & 15)) * 72 + ko);
#pragma unroll
            for (int i = 0; i < 4; ++i)
#pragma unroll
                for (int j = 0; j < 4; ++j)
                    acc[i][j] = __builtin_amdgcn_mfma_f32_16x16x32_bf16(af[i], bf[j], acc[i][j], 0, 0, 0);
        }
        __syncthreads();
    }
    const int cr = (lane >> 4) * 4, cc = lane & 15;
#pragma unroll
    for (int i = 0; i < 4; ++i) {
#pragma unroll
        for (int r = 0; r < 4; ++r) {
            const long row = m0 + wm + i * 16 + cr + r;
#pragma unroll
            for (int j = 0; j < 4; ++j) {
                const long col = n0 + wn + j * 16 + cc;
                if (OUT_BF16)
                    ((ushort*)Cv)[cOff + row * ldc + col] = f2b(acc[i][j][r] * cscale);
                else
                    ((float*)Cv)[cOff + row * ldc + col] = acc[i][j][r] * cscale;
            }
        }
    }
}

// ---------------- flash attention (round 10) ----------------
// d=128 MHA on khat/V. 4 waves x 16 q-rows. TWO fixed LDS buffers (K->bufK,
// V->bufV) + compact swizzled P slab = 40960 B exactly -> 4 blocks/CU,
// 16 waves/CU. Swapped QK^T (mfma(K,Q) -> scores[t][q=l15]) makes softmax
// reductions per-lane + 2 shuffles. Counted vmcnt(4); chunked XCD mapping.
#define PH_WAIT4()                                               \
    do {                                                         \
        asm volatile("s_waitcnt vmcnt(4) lgkmcnt(0)" ::: "memory"); \
        __builtin_amdgcn_s_barrier();                            \
    } while (0)
#define PH_WAIT0()                                               \
    do {                                                         \
        asm volatile("s_waitcnt vmcnt(0) lgkmcnt(0)" ::: "memory"); \
        __builtin_amdgcn_s_barrier();                            \
    } while (0)
#define RD_BAR()                                                 \
    do {                                                         \
        asm volatile("s_waitcnt lgkmcnt(0)" ::: "memory");       \
        __builtin_amdgcn_s_barrier();                            \
    } while (0)

__global__ __launch_bounds__(256, 4) void attn_k(const ushort* __restrict__ qbf,
                                                 const ushort* __restrict__ ktb,
                                                 const ushort* __restrict__ vtb,
                                                 ushort* __restrict__ ctxb,
                                                 int S, int T, int PAST) {
    __shared__ __align__(16) ushort bufK[64 * 128];   // [t][d], d-cols XOR-swizzled
    __shared__ __align__(16) ushort bufV[128 * 64];   // [d][t], t-cols XOR-swizzled
    __shared__ __align__(16) ushort pl[4][16][64];    // per-wave P [q][t], t XOR-swizzled
    const int tid = threadIdx.x, wid = tid >> 6, lane = tid & 63;
    // chunked XCD mapping (nwg divisible by 8): XCD k gets contiguous orig ids
    const int nsb = S >> 6;
    const int nwg = BB * HH * nsb;
    const int cpx = nwg >> 3;
    const int id = (int)blockIdx.x;
    const int orig = (id & 7) * cpx + (id >> 3);
    const int sblk = orig % nsb;
    const int h = (orig / nsb) % HH;
    const int b = orig / (nsb * HH);
    const int s0 = (nsb - 1 - sblk) * 64;  // longest-first within chunk

    const int g = lane >> 4, l15 = lane & 15, q8 = g << 3;
    const int swr = (l15 & 7) << 3;  // read-side XOR (ushort units)

    // Q fragments: per-head slice of x (scale folded into khat)
    bf16x8 qf[4];
    {
        const ushort* qb = qbf + ((long)b * S + s0 + wid * 16 + l15) * DV + h * DHD + q8;
#pragma unroll
        for (int kk = 0; kk < 4; ++kk) qf[kk] = *(const bf16x8*)(qb + kk * 32);
    }
    f32x4 cacc[8] = {};
    f32x4 sacc[4] = {};   // swapped: sacc[nf][r] = S[t = nf*16+g*4+r][q = l15]
    float mrow = -1e30f, lrow = 0.f;  // per-lane, q = wid*16 + l15
    const int rl = tid >> 4, cc16 = tid & 15;
    const int vr = tid >> 3, vc = tid & 7;
    const int nfull = (s0 + PAST) / 64;
    const ushort* kbase = ktb + (long)b * T * DV + h * DHD;
    const ushort* vbase = vtb + ((long)b * DV + h * DHD) * T;
    const int kcol = (cc16 ^ (rl & 7)) << 3;
    const int vcol = (vc ^ (vr & 7)) << 3;

    auto stageK = [&](int tt_) {
#pragma unroll
        for (int p = 0; p < 4; ++p)
            gll16(kbase + (long)(tt_ * 64 + p * 16 + rl) * DV + kcol, &bufK[p * 2048 + tid * 8]);
    };
    auto stageV = [&](int tt_) {
#pragma unroll
        for (int p = 0; p < 4; ++p)
            gll16(vbase + (long)(p * 32 + vr) * T + tt_ * 64 + vcol, &bufV[p * 2048 + tid * 8]);
    };

    stageK(0);
    stageV(0);

    for (int tt = 0; tt <= nfull; ++tt) {
        const bool last = (tt == nfull);
        // ---- phase A: wait K(tt); QK (swapped: out[t][q]) ----
        PH_WAIT4();
        __builtin_amdgcn_s_setprio(1);
#pragma unroll
        for (int kk = 0; kk < 4; ++kk) {
            const int ko = kk * 32 + q8;
#pragma unroll
            for (int nf = 0; nf < 4; ++nf) {
                bf16x8 af = *(const bf16x8*)(&bufK[(nf * 16 + l15) * 128 + (ko ^ swr)]);
                sacc[nf] = __builtin_amdgcn_mfma_f32_16x16x32_bf16(af, qf[kk], sacc[nf], 0, 0, 0);
            }
        }
        __builtin_amdgcn_s_setprio(0);
        RD_BAR();                       // all waves done reading bufK
        if (!last) stageK(tt + 1);      // overwrite bufK with next K
        // ---- phase B: wait V(tt); softmax + PV ----
        if (last) { PH_WAIT0(); } else { PH_WAIT4(); }
        float pm = -1e30f;
#pragma unroll
        for (int nf = 0; nf < 4; ++nf)
#pragma unroll
            for (int r = 0; r < 4; ++r) {
                float v = sacc[nf][r];
                if (last) {
                    int tl = nf * 16 + (g << 2) + r;
                    int ql = wid * 16 + l15;
                    if (tl > ql) v = -1e30f;
                }
                sacc[nf][r] = v;
                pm = fmaxf(pm, v);
            }
        pm = fmaxf(pm, __shfl_xor(pm, 16, 64));
        pm = fmaxf(pm, __shfl_xor(pm, 32, 64));
        if (__any(pm > mrow + 8.0f)) {
            float mn = fmaxf(mrow, pm);
            float al = __expf(mrow - mn);
            mrow = mn;
            lrow *= al;
#pragma unroll
            for (int r = 0; r < 4; ++r) {
                float alr = __shfl(al, (g << 2) + r, 64);  // al for q-row g*4+r
#pragma unroll
                for (int df = 0; df < 8; ++df) cacc[df][r] *= alr;
            }
        }
        float ps = 0.f;
#pragma unroll
        for (int nf = 0; nf < 4; ++nf)
#pragma unroll
            for (int r = 0; r < 4; ++r) {
                float p = __expf(sacc[nf][r] - mrow);
                sacc[nf][r] = p;
                ps += p;
            }
        ps += __shfl_xor(ps, 16, 64);
        ps += __shfl_xor(ps, 32, 64);
        lrow += ps;
        // P -> wave-private swizzled LDS: pl[wid][q=l15][t ^ swr]
#pragma unroll
        for (int nf = 0; nf < 4; ++nf)
#pragma unroll
            for (int r = 0; r < 4; ++r)
                pl[wid][l15][(nf * 16 + (g << 2) + r) ^ swr] = f2b(sacc[nf][r]);
#pragma unroll
        for (int nf = 0; nf < 4; ++nf) sacc[nf] = (f32x4){0.f, 0.f, 0.f, 0.f};
        // ctx += P * V
        __builtin_amdgcn_s_setprio(1);
#pragma unroll
        for (int kk = 0; kk < 2; ++kk) {
            bf16x8 a = *(const bf16x8*)(&pl[wid][l15][(kk * 32 + q8) ^ swr]);
#pragma unroll
            for (int df = 0; df < 8; ++df) {
                bf16x8 bv = *(const bf16x8*)(&bufV[(df * 16 + l15) * 64 + ((kk * 32 + q8) ^ swr)]);
                cacc[df] = __builtin_amdgcn_mfma_f32_16x16x32_bf16(a, bv, cacc[df], 0, 0, 0);
            }
        }
        __builtin_amdgcn_s_setprio(0);
        if (!last) {
            RD_BAR();                   // all waves done reading bufV
            stageV(tt + 1);
        }
    }
    // ---- epilogue ----
    const long rbase = (long)b * S + s0 + wid * 16 + (g << 2);
#pragma unroll
    for (int r = 0; r < 4; ++r) {
        float lr = __shfl(lrow, (g << 2) + r, 64);
        float inv = 1.0f / lr;
        const int d = h * DHD + l15;
#pragma unroll
        for (int df = 0; df < 8; ++df)
            ctxb[(rbase + r) * DV + d + df * 16] = f2b(cacc[df][r] * inv);
    }
}

extern "C" void kernel_launch(void* const* d_in, const int* in_sizes, int n_in,
                              void* d_out, int out_size, void* d_ws, size_t ws_size,
                              hipStream_t stream) {
    const float* x = (const float*)d_in[0];
    const float* kv = (const float*)d_in[1];
    const float* Wq = (const float*)d_in[2];
    const float* Wdkv = (const float*)d_in[3];
    const float* Wuk = (const float*)d_in[4];
    const float* Wuv = (const float*)d_in[5];
    const float* Wo = (const float*)d_in[6];
    const float* lng = (const float*)d_in[7];
    const float* lnbt = (const float*)d_in[8];
    const int S = in_sizes[0] / (BB * DV);     // 2048
    const int PAST = in_sizes[1] / (BB * LL);  // 2048
    const int T = S + PAST;                    // 4096

    float* out_p = (float*)d_out;                       // [B,S,D] f32
    float* ckv_out = out_p + (size_t)BB * S * DV;       // [B,T,L] f32

    char* w = (char*)d_ws;
    auto take = [&](size_t bytes) { char* p = w; w += (bytes + 255) & ~(size_t)255; return p; };
    ushort* xb    = (ushort*)take((size_t)BB * S * DV * 2);
    ushort* Wqb   = (ushort*)take((size_t)DV * DV * 2);
    ushort* WukT  = (ushort*)take((size_t)DV * LL * 2);   // [L][D] = Wuk^T
    ushort* Wdkvb = (ushort*)take((size_t)LL * DV * 2);
    ushort* Wuvb  = (ushort*)take((size_t)DV * LL * 2);
    ushort* Wob   = (ushort*)take((size_t)DV * DV * 2);
    ushort* absb  = (ushort*)take((size_t)DV * LL * 2);   // [D][L] = Wq@Wuk (scaled)
    float*  cpre  = (float*)take((size_t)BB * S * LL * 4);
    ushort* ckvb  = (ushort*)take((size_t)BB * T * LL * 2);
    ushort* vtb   = (ushort*)take((size_t)BB * DV * T * 2);  // [B][D][T]
    ushort* ktb   = (ushort*)take((size_t)BB * T * DV * 2);  // [B][T][D] khat
    ushort* ctxb  = (ushort*)take((size_t)BB * S * DV * 2);

    auto cvt = [&](const float* in, ushort* op, long n) {
        long nb = (n / 4 + 255) / 256;
        if (nb > 2048) nb = 2048;
        cvt_k<<<dim3((unsigned)nb), dim3(256), 0, stream>>>(in, op, n);
    };
    cvt(x, xb, (long)BB * S * DV);
    cvt(Wq, Wqb, (long)DV * DV);
    cvt(Wdkv, Wdkvb, (long)LL * DV);
    cvt(Wuv, Wuvb, (long)DV * LL);
    cvt(Wo, Wob, (long)DV * DV);
    transpose_cvt_k<<<dim3(LL / 64, DV / 64), dim3(256), 0, stream>>>(Wuk, WukT, DV, LL);
    kvcopy_k<<<dim3(2048), dim3(256), 0, stream>>>(kv, ckv_out, ckvb, PAST, T);

    // absorbed[j,l] = sum_i Wq[j,i]*Wuk[i,l], scaled by 1/sqrt(dh) -> [D][L]
    gemm_nt<true><<<dim3(DV / 128, LL / 128, 1), dim3(256), 0, stream>>>(
        Wqb, WukT, absb, DV, DV, DV, LL, 0, 0, 0, 0, 0, 0, 1, 0.08838834764831845f);
    // c_pre = x * Wdkv^T  (f32)
    gemm_nt<false><<<dim3(BB * S / 128, LL / 128, 1), dim3(256), 0, stream>>>(
        xb, Wdkvb, cpre, DV, DV, DV, LL, 0, 0, 0, 0, 0, 0, 1, 1.0f);
    ln_k<<<dim3(BB * S / 4), dim3(256), 0, stream>>>(cpre, lng, lnbt, ckv_out, ckvb, S, PAST, T);
    // Vt[b] = Wuv * ckv[b]^T : [D][T] bf16
    gemm_nt<true><<<dim3(DV / 128, T / 128, BB), dim3(256), 0, stream>>>(
        Wuvb, ckvb, vtb, LL, LL, LL, T, 0, 0, (long)T * LL, 0, (long)DV * T, 0, 1, 1.0f);
    // khat[b] = ckv[b] @ absorbed^T : [T][D] bf16
    gemm_nt<true><<<dim3(T / 128, DV / 128, BB), dim3(256), 0, stream>>>(
        ckvb, absb, ktb, LL, LL, LL, DV, (long)T * LL, 0, 0, 0, (long)T * DV, 0, 1, 1.0f);
    // attention (d=128 MHA; Q = per-head slice of x)
    attn_k<<<dim3(BB * HH * (S / 64)), dim3(256), 0, stream>>>(xb, ktb, vtb, ctxb, S, T, PAST);
    // out = ctx * Wo^T (f32)
    gemm_nt<false><<<dim3(BB * S / 128, DV / 128, 1), dim3(256), 0, stream>>>(
        ctxb, Wob, out_p, DV, DV, DV, DV, 0, 0, 0, 0, 0, 0, 1, 1.0f);
}